// Round 1
// baseline (308.085 us; speedup 1.0000x reference)
//
#include <hip/hip_runtime.h>
#include <hip/hip_bf16.h>
#include <math.h>

typedef __bf16 bf16_t;
typedef __bf16 bf16x8 __attribute__((ext_vector_type(8)));
typedef float f32x4 __attribute__((ext_vector_type(4)));

#define NB 1024
#define NN 75
#define KF 512
#define F1 256

// ---------------------------------------------------------------------------
// Kernel 0: W [512][256] fp32  ->  Wt [256][512] bf16 (transposed, k-contiguous)
// ---------------------------------------------------------------------------
__global__ __launch_bounds__(256) void wt_kernel(const float* __restrict__ W,
                                                 bf16_t* __restrict__ Wt) {
    __shared__ float tile[64][65];
    const int kb = blockIdx.x * 64;   // k block (8 blocks)
    const int nb = blockIdx.y * 64;   // n block (4 blocks)
    const int tc = threadIdx.x & 63;
    const int tr = threadIdx.x >> 6;
#pragma unroll
    for (int r = tr; r < 64; r += 4)
        tile[r][tc] = W[(size_t)(kb + r) * F1 + nb + tc];
    __syncthreads();
#pragma unroll
    for (int r = tr; r < 64; r += 4)
        Wt[(size_t)(nb + r) * KF + kb + tc] = (bf16_t)tile[tc][r];
}

// ---------------------------------------------------------------------------
// Kernel 1: h = X @ W  (bf16 MFMA), h written to d_out[..., 256:512]
// Tile: BM=64, BN=256 (full), BK=32. 4 waves, wave w owns rows w*16..w*16+15.
// ---------------------------------------------------------------------------
__global__ __launch_bounds__(256) void gemm_kernel(const float* __restrict__ X,
                                                   const bf16_t* __restrict__ Wt,
                                                   float* __restrict__ out) {
    __shared__ __align__(16) bf16_t Asm[64 * 32];    // [m][k]
    __shared__ __align__(16) bf16_t Bsm[256 * 32];   // [n][k] (transposed W)
    const int t = threadIdx.x;
    const int w = t >> 6;
    const int l = t & 63;
    const int m0 = blockIdx.x * 64;

    f32x4 acc[16];
#pragma unroll
    for (int i = 0; i < 16; ++i) acc[i] = (f32x4){0.f, 0.f, 0.f, 0.f};

    // staging coordinates: thread t handles row (t>>2), k-chunk (t&3)*8
    const int ar = t >> 2;
    const int ak = (t & 3) * 8;
    const float* xptr = X + (size_t)(m0 + ar) * KF + ak;

    // fragment read pointers
    const int koff = (l >> 4) * 8;
    const bf16_t* afrag_p = &Asm[(w * 16 + (l & 15)) * 32 + koff];
    const bf16_t* bfrag_p = &Bsm[(l & 15) * 32 + koff];

    for (int ks = 0; ks < 16; ++ks) {
        const int k0 = ks * 32;
        // stage A tile: fp32 -> bf16 (RNE via __bf16 cast)
        const float4 x0 = *(const float4*)(xptr + k0);
        const float4 x1 = *(const float4*)(xptr + k0 + 4);
        bf16x8 av;
        av[0] = (bf16_t)x0.x; av[1] = (bf16_t)x0.y;
        av[2] = (bf16_t)x0.z; av[3] = (bf16_t)x0.w;
        av[4] = (bf16_t)x1.x; av[5] = (bf16_t)x1.y;
        av[6] = (bf16_t)x1.z; av[7] = (bf16_t)x1.w;
        *(bf16x8*)&Asm[ar * 32 + ak] = av;
        // stage B tile: already bf16, straight 16B copies (L2-resident)
#pragma unroll
        for (int p = 0; p < 4; ++p) {
            const int row = p * 64 + ar;
            *(uint4*)&Bsm[row * 32 + ak] =
                *(const uint4*)(Wt + (size_t)row * KF + k0 + ak);
        }
        __syncthreads();
        const bf16x8 af = *(const bf16x8*)afrag_p;
#pragma unroll
        for (int nt = 0; nt < 16; ++nt) {
            const bf16x8 bfv = *(const bf16x8*)(bfrag_p + nt * 16 * 32);
            acc[nt] = __builtin_amdgcn_mfma_f32_16x16x32_bf16(af, bfv, acc[nt], 0, 0, 0);
        }
        __syncthreads();
    }

    // epilogue: D[row=(l>>4)*4+j][col=l&15] per n-tile; h -> channels 256..511
    const int mrow = m0 + w * 16 + (l >> 4) * 4;
    const int ncol = l & 15;
#pragma unroll
    for (int nt = 0; nt < 16; ++nt) {
#pragma unroll
        for (int j = 0; j < 4; ++j) {
            out[(size_t)(mrow + j) * 512 + 256 + nt * 16 + ncol] = acc[nt][j];
        }
    }
}

// ---------------------------------------------------------------------------
// Kernel 2: per-batch attention + aggregation.
// One block per b. h[b] (75x256 f32) in LDS; att dots, masked softmax over j
// (lane j holds e_j), out[b,i,:] = sum_j alpha_ij h[b,j,:].
// ---------------------------------------------------------------------------
__global__ __launch_bounds__(256) void attn_kernel(const int* __restrict__ Adj,
                                                   const float* __restrict__ avec,
                                                   float* __restrict__ out) {
    __shared__ __align__(16) float hs[NN * F1];   // 76.8 KB
    __shared__ float a0s[F1], a1s[F1];
    __shared__ float att0[NN], att1[NN];
    const int b = blockIdx.x;
    const int t = threadIdx.x;
    const int w = t >> 6;
    const int l = t & 63;
    a0s[t] = avec[t];
    a1s[t] = avec[F1 + t];
    float* outb = out + (size_t)b * NN * 512;

    // load h[b] from d_out[..., 256:512]
#pragma unroll
    for (int it = 0; it < 19; ++it) {
        const int r = it * 4 + w;
        if (r < NN) {
            *(float4*)&hs[r * F1 + l * 4] =
                *(const float4*)(outb + r * 512 + 256 + l * 4);
        }
    }
    __syncthreads();

    // attention dot products: wave-parallel 256-length dots, shfl reduce
    for (int n = w; n < NN; n += 4) {
        const float4 h4  = *(const float4*)&hs[n * F1 + l * 4];
        const float4 a04 = *(const float4*)&a0s[l * 4];
        const float4 a14 = *(const float4*)&a1s[l * 4];
        float p0 = h4.x * a04.x + h4.y * a04.y + h4.z * a04.z + h4.w * a04.w;
        float p1 = h4.x * a14.x + h4.y * a14.y + h4.z * a14.z + h4.w * a14.w;
#pragma unroll
        for (int off = 32; off; off >>= 1) {
            p0 += __shfl_xor(p0, off);
            p1 += __shfl_xor(p1, off);
        }
        if (l == 0) { att0[n] = p0; att1[n] = p1; }
    }
    __syncthreads();

    // softmax + aggregation, row i per wave round-robin
    for (int i = w; i < NN; i += 4) {
        const float a0i = att0[i];
        float e1;
        {
            float x = a0i + att1[l];                   // all lanes: j=l < 75
            x = x > 0.f ? x : 0.2f * x;
            e1 = x - 1.0e9f * (1.f - (float)Adj[i * NN + l]);
        }
        float e2 = -INFINITY;
        if (l < NN - 64) {                             // j = l+64 in [64,75)
            float x = a0i + att1[l + 64];
            x = x > 0.f ? x : 0.2f * x;
            e2 = x - 1.0e9f * (1.f - (float)Adj[i * NN + l + 64]);
        }
        float mx = fmaxf(e1, e2);
#pragma unroll
        for (int off = 32; off; off >>= 1) mx = fmaxf(mx, __shfl_xor(mx, off));
        const float p1 = __expf(e1 - mx);
        const float p2 = (l < NN - 64) ? __expf(e2 - mx) : 0.f;
        float s = p1 + p2;
#pragma unroll
        for (int off = 32; off; off >>= 1) s += __shfl_xor(s, off);
        const float rs = 1.f / s;

        float acc0 = 0.f, acc1 = 0.f, acc2 = 0.f, acc3 = 0.f;
        for (int j = 0; j < NN; ++j) {
            const float aj = (j < 64) ? __shfl(p1, j) : __shfl(p2, j - 64);
            acc0 += aj * hs[j * F1 + l];
            acc1 += aj * hs[j * F1 + 64 + l];
            acc2 += aj * hs[j * F1 + 128 + l];
            acc3 += aj * hs[j * F1 + 192 + l];
        }
        float* orow = outb + (size_t)i * 512;
        orow[l]       = acc0 * rs;
        orow[64 + l]  = acc1 * rs;
        orow[128 + l] = acc2 * rs;
        orow[192 + l] = acc3 * rs;
    }
}

// ---------------------------------------------------------------------------
extern "C" void kernel_launch(void* const* d_in, const int* in_sizes, int n_in,
                              void* d_out, int out_size, void* d_ws, size_t ws_size,
                              hipStream_t stream) {
    const float* X = (const float*)d_in[0];   // [1024,75,512] f32
    const int*   A = (const int*)d_in[1];     // [75,75] i32
    const float* W = (const float*)d_in[2];   // [512,256] f32
    const float* a = (const float*)d_in[3];   // [2,256,1] f32
    float* out = (float*)d_out;               // [1024,75,512] f32
    bf16_t* Wt = (bf16_t*)d_ws;               // 256*512*2 = 256 KB scratch

    wt_kernel<<<dim3(KF / 64, F1 / 64), 256, 0, stream>>>(W, Wt);
    gemm_kernel<<<(NB * NN) / 64, 256, 0, stream>>>(X, Wt, out);
    attn_kernel<<<NB, 256, 0, stream>>>(A, a, out);
}

// Round 2
// 189.756 us; speedup vs baseline: 1.6236x; 1.6236x over previous
//
#include <hip/hip_runtime.h>
#include <hip/hip_bf16.h>
#include <math.h>

typedef __bf16 bf16_t;
typedef __bf16 bf16x4_t __attribute__((ext_vector_type(4)));
typedef __bf16 bf16x8 __attribute__((ext_vector_type(8)));
typedef float f32x4 __attribute__((ext_vector_type(4)));

#define NB 1024
#define NN 75
#define KF 512
#define F1 256
#define KP 96      // padded K (j) for MFMA: 3 k-steps of 32
#define HSTR 100   // LDS row stride in bf16 elems (200 B = 50 dwords; odd/2 -> bank spread, mult-of-4 elems -> 8B align)

// ---------------------------------------------------------------------------
// Kernel 0: W [512][256] fp32 -> Wt [256][512] bf16 (transposed, k-contiguous)
// ---------------------------------------------------------------------------
__global__ __launch_bounds__(256) void wt_kernel(const float* __restrict__ W,
                                                 bf16_t* __restrict__ Wt) {
    __shared__ float tile[64][65];
    const int kb = blockIdx.x * 64;
    const int nb = blockIdx.y * 64;
    const int tc = threadIdx.x & 63;
    const int tr = threadIdx.x >> 6;
#pragma unroll
    for (int r = tr; r < 64; r += 4)
        tile[r][tc] = W[(size_t)(kb + r) * F1 + nb + tc];
    __syncthreads();
#pragma unroll
    for (int r = tr; r < 64; r += 4)
        Wt[(size_t)(nb + r) * KF + kb + tc] = (bf16_t)tile[tc][r];
}

// ---------------------------------------------------------------------------
// Kernel 1: h = X @ W (bf16 MFMA) -> d_out[..., 256:512]   (unchanged, passed)
// ---------------------------------------------------------------------------
__global__ __launch_bounds__(256) void gemm_kernel(const float* __restrict__ X,
                                                   const bf16_t* __restrict__ Wt,
                                                   float* __restrict__ out) {
    __shared__ __align__(16) bf16_t Asm[64 * 32];
    __shared__ __align__(16) bf16_t Bsm[256 * 32];
    const int t = threadIdx.x;
    const int w = t >> 6;
    const int l = t & 63;
    const int m0 = blockIdx.x * 64;

    f32x4 acc[16];
#pragma unroll
    for (int i = 0; i < 16; ++i) acc[i] = (f32x4){0.f, 0.f, 0.f, 0.f};

    const int ar = t >> 2;
    const int ak = (t & 3) * 8;
    const float* xptr = X + (size_t)(m0 + ar) * KF + ak;

    const int koff = (l >> 4) * 8;
    const bf16_t* afrag_p = &Asm[(w * 16 + (l & 15)) * 32 + koff];
    const bf16_t* bfrag_p = &Bsm[(l & 15) * 32 + koff];

    for (int ks = 0; ks < 16; ++ks) {
        const int k0 = ks * 32;
        const float4 x0 = *(const float4*)(xptr + k0);
        const float4 x1 = *(const float4*)(xptr + k0 + 4);
        bf16x8 av;
        av[0] = (bf16_t)x0.x; av[1] = (bf16_t)x0.y;
        av[2] = (bf16_t)x0.z; av[3] = (bf16_t)x0.w;
        av[4] = (bf16_t)x1.x; av[5] = (bf16_t)x1.y;
        av[6] = (bf16_t)x1.z; av[7] = (bf16_t)x1.w;
        *(bf16x8*)&Asm[ar * 32 + ak] = av;
#pragma unroll
        for (int p = 0; p < 4; ++p) {
            const int row = p * 64 + ar;
            *(uint4*)&Bsm[row * 32 + ak] =
                *(const uint4*)(Wt + (size_t)row * KF + k0 + ak);
        }
        __syncthreads();
        const bf16x8 af = *(const bf16x8*)afrag_p;
#pragma unroll
        for (int nt = 0; nt < 16; ++nt) {
            const bf16x8 bfv = *(const bf16x8*)(bfrag_p + nt * 16 * 32);
            acc[nt] = __builtin_amdgcn_mfma_f32_16x16x32_bf16(af, bfv, acc[nt], 0, 0, 0);
        }
        __syncthreads();
    }

    const int mrow = m0 + w * 16 + (l >> 4) * 4;
    const int ncol = l & 15;
#pragma unroll
    for (int nt = 0; nt < 16; ++nt) {
#pragma unroll
        for (int j = 0; j < 4; ++j) {
            out[(size_t)(mrow + j) * 512 + 256 + nt * 16 + ncol] = acc[nt][j];
        }
    }
}

// ---------------------------------------------------------------------------
// Kernel 2: per-batch attention; aggregation via MFMA.
//  phase 1: load h rows (f32), fuse att dot partials, 4x4 register transpose
//           -> hT bf16 [256][HSTR] in LDS (j-contiguous)
//  phase 2: masked softmax per row -> alpha bf16 [80][HSTR] (zero-padded)
//  phase 3: C[i][ch] = sum_j alpha[i][j] hT[ch][j] via mfma_f32_16x16x32_bf16
// ---------------------------------------------------------------------------
__global__ __launch_bounds__(256) void attn_kernel(const int* __restrict__ Adj,
                                                   const float* __restrict__ avec,
                                                   float* __restrict__ out) {
    __shared__ __align__(16) bf16_t hT[256 * HSTR];   // 51200 B
    __shared__ __align__(16) bf16_t alp[80 * HSTR];   // 16000 B
    __shared__ float a0s[F1], a1s[F1];
    __shared__ float attp0[4][80], attp1[4][80];
    __shared__ float att0s[80], att1s[80];

    const int b = blockIdx.x;
    const int t = threadIdx.x;
    const int w = t >> 6;
    const int l = t & 63;
    const int lc = l & 15;   // 0..15
    const int lr = l >> 4;   // 0..3
    float* outb = out + (size_t)b * NN * 512;

    // ---- phase 0: stage a-vectors, zero hT k-pad (j = 80..95) ----
    a0s[t] = avec[t];
    a1s[t] = avec[F1 + t];
    {
        int* z = (int*)&hT[t * HSTR + 80];   // byte offset 160 in row t (8B-aligned)
#pragma unroll
        for (int k = 0; k < 8; ++k) z[k] = 0;
    }
    __syncthreads();

    // ---- phase 1: load + att partials + transpose-store ----
    const int c0 = w * 64 + lc * 4;          // this lane's 4-channel chunk
    const float4 a04 = *(const float4*)&a0s[c0];
    const float4 a14 = *(const float4*)&a1s[c0];
#pragma unroll
    for (int jp = 0; jp < 5; ++jp) {
        const int j0 = jp * 16 + lr * 4;
        float hr[4][4];
#pragma unroll
        for (int r = 0; r < 4; ++r) {
            if (j0 + r < NN) {
                const float4 v = *(const float4*)(outb + (size_t)(j0 + r) * 512 + 256 + c0);
                hr[r][0] = v.x; hr[r][1] = v.y; hr[r][2] = v.z; hr[r][3] = v.w;
            } else {
                hr[r][0] = hr[r][1] = hr[r][2] = hr[r][3] = 0.f;
            }
        }
        float p0[4], p1[4];
#pragma unroll
        for (int r = 0; r < 4; ++r) {
            p0[r] = hr[r][0] * a04.x + hr[r][1] * a04.y + hr[r][2] * a04.z + hr[r][3] * a04.w;
            p1[r] = hr[r][0] * a14.x + hr[r][1] * a14.y + hr[r][2] * a14.z + hr[r][3] * a14.w;
        }
#pragma unroll
        for (int off = 1; off < 16; off <<= 1) {
#pragma unroll
            for (int r = 0; r < 4; ++r) {
                p0[r] += __shfl_xor(p0[r], off);
                p1[r] += __shfl_xor(p1[r], off);
            }
        }
        if (lc == 0) {
#pragma unroll
            for (int r = 0; r < 4; ++r) {
                attp0[w][j0 + r] = p0[r];
                attp1[w][j0 + r] = p1[r];
            }
        }
        // transposed bf16 store: hT[c0+cc][j0..j0+3]
#pragma unroll
        for (int cc = 0; cc < 4; ++cc) {
            bf16x4_t v;
            v[0] = (bf16_t)hr[0][cc]; v[1] = (bf16_t)hr[1][cc];
            v[2] = (bf16_t)hr[2][cc]; v[3] = (bf16_t)hr[3][cc];
            *(bf16x4_t*)&hT[(c0 + cc) * HSTR + j0] = v;
        }
    }
    __syncthreads();

    // ---- phase 1b: sum per-wave att partials ----
    if (t < 80)       att0s[t]      = attp0[0][t] + attp0[1][t] + attp0[2][t] + attp0[3][t];
    else if (t < 160) att1s[t - 80] = attp1[0][t - 80] + attp1[1][t - 80] + attp1[2][t - 80] + attp1[3][t - 80];
    __syncthreads();

    // ---- phase 2: masked softmax, write alpha row (bf16, zero-padded) ----
    for (int i = w; i < NN; i += 4) {
        const float a0i = att0s[i];
        float e1;
        {
            float x = a0i + att1s[l];
            x = x > 0.f ? x : 0.2f * x;
            e1 = x - 1.0e9f * (1.f - (float)Adj[i * NN + l]);
        }
        float e2 = -INFINITY;
        if (l < NN - 64) {
            float x = a0i + att1s[l + 64];
            x = x > 0.f ? x : 0.2f * x;
            e2 = x - 1.0e9f * (1.f - (float)Adj[i * NN + l + 64]);
        }
        float mx = fmaxf(e1, e2);
#pragma unroll
        for (int off = 32; off; off >>= 1) mx = fmaxf(mx, __shfl_xor(mx, off));
        const float p1v = __expf(e1 - mx);
        const float p2v = (l < NN - 64) ? __expf(e2 - mx) : 0.f;
        float s = p1v + p2v;
#pragma unroll
        for (int off = 32; off; off >>= 1) s += __shfl_xor(s, off);
        const float rs = 1.f / s;

        alp[i * HSTR + l] = (bf16_t)(p1v * rs);
        if (l < 32)   // j = 64+l covers 64..95: values for j<75, zeros for K-pad
            alp[i * HSTR + 64 + l] = (l < NN - 64) ? (bf16_t)(p2v * rs) : (bf16_t)0.f;
    }
    __syncthreads();

    // ---- phase 3: out[i][ch] = sum_j alpha[i][j] * hT[ch][j] via MFMA ----
    for (int mt = w; mt < 5; mt += 4) {   // 5 M-tiles of 16; wave0 also does mt=4
        f32x4 acc[16];
#pragma unroll
        for (int i = 0; i < 16; ++i) acc[i] = (f32x4){0.f, 0.f, 0.f, 0.f};
#pragma unroll
        for (int ks = 0; ks < 3; ++ks) {
            bf16x8 af;
            {
                const bf16_t* p = &alp[(mt * 16 + lc) * HSTR + ks * 32 + lr * 8];
                ((uint2*)&af)[0] = *(const uint2*)p;
                ((uint2*)&af)[1] = *(const uint2*)(p + 4);
            }
#pragma unroll
            for (int nt = 0; nt < 16; ++nt) {
                bf16x8 bfv;
                const bf16_t* q = &hT[(nt * 16 + lc) * HSTR + ks * 32 + lr * 8];
                ((uint2*)&bfv)[0] = *(const uint2*)q;
                ((uint2*)&bfv)[1] = *(const uint2*)(q + 4);
                acc[nt] = __builtin_amdgcn_mfma_f32_16x16x32_bf16(af, bfv, acc[nt], 0, 0, 0);
            }
        }
        const int rbase = mt * 16 + lr * 4;
#pragma unroll
        for (int nt = 0; nt < 16; ++nt) {
#pragma unroll
            for (int jj = 0; jj < 4; ++jj) {
                const int row = rbase + jj;
                if (row < NN)
                    outb[(size_t)row * 512 + nt * 16 + lc] = acc[nt][jj];
            }
        }
    }
}

// ---------------------------------------------------------------------------
extern "C" void kernel_launch(void* const* d_in, const int* in_sizes, int n_in,
                              void* d_out, int out_size, void* d_ws, size_t ws_size,
                              hipStream_t stream) {
    const float* X = (const float*)d_in[0];
    const int*   A = (const int*)d_in[1];
    const float* W = (const float*)d_in[2];
    const float* a = (const float*)d_in[3];
    float* out = (float*)d_out;
    bf16_t* Wt = (bf16_t*)d_ws;

    wt_kernel<<<dim3(KF / 64, F1 / 64), 256, 0, stream>>>(W, Wt);
    gemm_kernel<<<(NB * NN) / 64, 256, 0, stream>>>(X, Wt, out);
    attn_kernel<<<NB, 256, 0, stream>>>(A, a, out);
}

// Round 3
// 163.156 us; speedup vs baseline: 1.8883x; 1.1630x over previous
//
#include <hip/hip_runtime.h>
#include <hip/hip_bf16.h>
#include <math.h>

typedef __bf16 bf16_t;
typedef __bf16 bf16x4_t __attribute__((ext_vector_type(4)));
typedef __bf16 bf16x8 __attribute__((ext_vector_type(8)));
typedef float f32x4 __attribute__((ext_vector_type(4)));

#define NB 1024
#define NN 75
#define KF 512
#define F1 256
#define HSTR 100   // hT/alp row stride (bf16): >=96, 8B-aligned, bank-spread (50 dw)
#define XSTR 40    // X tile row stride (bf16): 32 + 8 pad, 16B-aligned rows
#define WSTR 40    // W tile row stride (bf16)

// ---------------------------------------------------------------------------
// Kernel 0: W [512][256] fp32 -> Wt [256][512] bf16 (transposed, k-contiguous)
// ---------------------------------------------------------------------------
__global__ __launch_bounds__(256) void wt_kernel(const float* __restrict__ W,
                                                 bf16_t* __restrict__ Wt) {
    __shared__ float tile[64][65];
    const int kb = blockIdx.x * 64;
    const int nb = blockIdx.y * 64;
    const int tc = threadIdx.x & 63;
    const int tr = threadIdx.x >> 6;
#pragma unroll
    for (int r = tr; r < 64; r += 4)
        tile[r][tc] = W[(size_t)(kb + r) * F1 + nb + tc];
    __syncthreads();
#pragma unroll
    for (int r = tr; r < 64; r += 4)
        Wt[(size_t)(nb + r) * KF + kb + tc] = (bf16_t)tile[tc][r];
}

// ---------------------------------------------------------------------------
// Fused kernel: one block per batch.
//   G: h = X[b] @ Wt via MFMA (dbuf LDS, acc in regs, h rows 75..79 = 0)
//   T: h -> out[...,256:512]; acc -> hT bf16 LDS; att partials via shfl
//   S: masked softmax -> alp bf16 LDS
//   P: out[...,0:256] = alpha @ h via MFMA
// Wave w owns channels [w*64, w*64+64): nt-split, balanced.
// ---------------------------------------------------------------------------
__global__ __launch_bounds__(256, 2) void fused_kernel(
    const float* __restrict__ X, const bf16_t* __restrict__ Wt,
    const int* __restrict__ Adj, const float* __restrict__ avec,
    float* __restrict__ out) {

    // union LDS: gemm tiles (53760 B) vs hT+alp (67200 B)
    __shared__ __align__(16) char smem[67200];
    bf16_t* Xs  = (bf16_t*)smem;                 // [2][80][XSTR] = 12800 B
    bf16_t* Ws  = (bf16_t*)(smem + 12800);       // [2][256][WSTR] = 40960 B
    bf16_t* hT  = (bf16_t*)smem;                 // [256][HSTR] = 51200 B
    bf16_t* alp = (bf16_t*)(smem + 51200);       // [80][HSTR]  = 16000 B
    __shared__ float a0s[F1], a1s[F1];
    __shared__ float attp0[4][80], attp1[4][80];
    __shared__ float att0s[80], att1s[80];

    const int b = blockIdx.x;
    const int t = threadIdx.x;
    const int w = t >> 6;
    const int l = t & 63;
    const int lc = l & 15;
    const int lr = l >> 4;
    const float* Xb = X + (size_t)b * NN * KF;
    float* outb = out + (size_t)b * NN * 512;

    a0s[t] = avec[t];
    a1s[t] = avec[F1 + t];

    // staging coords: X unit = 8 k-elems of one row; 320 units over 256 threads
    const int xrow0 = t >> 2;
    const int xkc   = (t & 3) * 8;
    const int xrow1 = 64 + (t >> 2);   // only t<64
    const int wrow  = t >> 2;          // Wt rows wrow + 64p, p=0..3
    const int wq    = t & 3;           // 16B chunk within 64B row-slice

    f32x4 acc[5][4];
#pragma unroll
    for (int i = 0; i < 5; ++i)
#pragma unroll
        for (int j = 0; j < 4; ++j) acc[i][j] = (f32x4){0.f, 0.f, 0.f, 0.f};

    // ---- prologue: stage k-step 0 into buffer 0 ----
    {
        const float* xp = Xb + (size_t)xrow0 * KF + xkc;
        const float4 x0 = *(const float4*)xp;
        const float4 x1 = *(const float4*)(xp + 4);
        bf16x8 v;
        v[0]=(bf16_t)x0.x; v[1]=(bf16_t)x0.y; v[2]=(bf16_t)x0.z; v[3]=(bf16_t)x0.w;
        v[4]=(bf16_t)x1.x; v[5]=(bf16_t)x1.y; v[6]=(bf16_t)x1.z; v[7]=(bf16_t)x1.w;
        *(bf16x8*)&Xs[xrow0 * XSTR + xkc] = v;
        if (t < 64) {
            bf16x8 v1;
#pragma unroll
            for (int k = 0; k < 8; ++k) v1[k] = (bf16_t)0.f;
            if (xrow1 < NN) {
                const float* xp1 = Xb + (size_t)xrow1 * KF + xkc;
                const float4 y0 = *(const float4*)xp1;
                const float4 y1 = *(const float4*)(xp1 + 4);
                v1[0]=(bf16_t)y0.x; v1[1]=(bf16_t)y0.y; v1[2]=(bf16_t)y0.z; v1[3]=(bf16_t)y0.w;
                v1[4]=(bf16_t)y1.x; v1[5]=(bf16_t)y1.y; v1[6]=(bf16_t)y1.z; v1[7]=(bf16_t)y1.w;
            }
            *(bf16x8*)&Xs[xrow1 * XSTR + xkc] = v1;
        }
#pragma unroll
        for (int p = 0; p < 4; ++p) {
            const uint4 wv = ((const uint4*)(Wt + (size_t)(wrow + 64 * p) * KF))[wq];
            *(uint4*)&Ws[(wrow + 64 * p) * WSTR + wq * 8] = wv;
        }
    }
    __syncthreads();

    // ---- phase G: K-loop, double-buffered ----
    for (int ks = 0; ks < 16; ++ks) {
        const int cur = ks & 1;
        const bf16_t* Xc = Xs + cur * 80 * XSTR;
        const bf16_t* Wc = Ws + cur * 256 * WSTR;

        bf16x8 xv0, xv1;
        uint4 wv[4];
        if (ks < 15) {
            const int k0 = (ks + 1) * 32;
            {
                const float* xp = Xb + (size_t)xrow0 * KF + k0 + xkc;
                const float4 x0 = *(const float4*)xp;
                const float4 x1 = *(const float4*)(xp + 4);
                xv0[0]=(bf16_t)x0.x; xv0[1]=(bf16_t)x0.y; xv0[2]=(bf16_t)x0.z; xv0[3]=(bf16_t)x0.w;
                xv0[4]=(bf16_t)x1.x; xv0[5]=(bf16_t)x1.y; xv0[6]=(bf16_t)x1.z; xv0[7]=(bf16_t)x1.w;
            }
#pragma unroll
            for (int k = 0; k < 8; ++k) xv1[k] = (bf16_t)0.f;
            if (t < 64 && xrow1 < NN) {
                const float* xp1 = Xb + (size_t)xrow1 * KF + k0 + xkc;
                const float4 y0 = *(const float4*)xp1;
                const float4 y1 = *(const float4*)(xp1 + 4);
                xv1[0]=(bf16_t)y0.x; xv1[1]=(bf16_t)y0.y; xv1[2]=(bf16_t)y0.z; xv1[3]=(bf16_t)y0.w;
                xv1[4]=(bf16_t)y1.x; xv1[5]=(bf16_t)y1.y; xv1[6]=(bf16_t)y1.z; xv1[7]=(bf16_t)y1.w;
            }
#pragma unroll
            for (int p = 0; p < 4; ++p)
                wv[p] = ((const uint4*)(Wt + (size_t)(wrow + 64 * p) * KF + k0))[wq];
        }

        bf16x8 af[5];
#pragma unroll
        for (int mt = 0; mt < 5; ++mt)
            af[mt] = *(const bf16x8*)&Xc[(mt * 16 + lc) * XSTR + lr * 8];
#pragma unroll
        for (int ntl = 0; ntl < 4; ++ntl) {
            const bf16x8 bv = *(const bf16x8*)&Wc[(w * 64 + ntl * 16 + lc) * WSTR + lr * 8];
#pragma unroll
            for (int mt = 0; mt < 5; ++mt)
                acc[mt][ntl] = __builtin_amdgcn_mfma_f32_16x16x32_bf16(af[mt], bv, acc[mt][ntl], 0, 0, 0);
        }
        __syncthreads();
        if (ks < 15) {
            const int nxt = cur ^ 1;
            bf16_t* Xn = Xs + nxt * 80 * XSTR;
            bf16_t* Wn = Ws + nxt * 256 * WSTR;
            *(bf16x8*)&Xn[xrow0 * XSTR + xkc] = xv0;
            if (t < 64) *(bf16x8*)&Xn[xrow1 * XSTR + xkc] = xv1;
#pragma unroll
            for (int p = 0; p < 4; ++p)
                *(uint4*)&Wn[(wrow + 64 * p) * WSTR + wq * 8] = wv[p];
        }
        __syncthreads();
    }

    // ---- phase T: h stores, hT build, att partials ----
    {   // zero hT pad columns j = 80..95 (row = channel t)
        uint2* zp = (uint2*)&hT[t * HSTR + 80];
        const uint2 z2 = {0u, 0u};
#pragma unroll
        for (int k = 0; k < 4; ++k) zp[k] = z2;
    }
    float a0c[4], a1c[4];
#pragma unroll
    for (int ntl = 0; ntl < 4; ++ntl) {
        a0c[ntl] = a0s[w * 64 + ntl * 16 + lc];
        a1c[ntl] = a1s[w * 64 + ntl * 16 + lc];
    }
    float p0[5][4], p1[5][4];
#pragma unroll
    for (int mt = 0; mt < 5; ++mt)
#pragma unroll
        for (int j = 0; j < 4; ++j) { p0[mt][j] = 0.f; p1[mt][j] = 0.f; }

#pragma unroll
    for (int mt = 0; mt < 5; ++mt) {
#pragma unroll
        for (int ntl = 0; ntl < 4; ++ntl) {
            const f32x4 v = acc[mt][ntl];
            const int ch = w * 64 + ntl * 16 + lc;
#pragma unroll
            for (int j = 0; j < 4; ++j) {
                const int row = mt * 16 + lr * 4 + j;
                if (row < NN) outb[(size_t)row * 512 + 256 + ch] = v[j];
                p0[mt][j] += v[j] * a0c[ntl];
                p1[mt][j] += v[j] * a1c[ntl];
            }
            bf16x4_t hv;
            hv[0] = (bf16_t)v[0]; hv[1] = (bf16_t)v[1];
            hv[2] = (bf16_t)v[2]; hv[3] = (bf16_t)v[3];
            *(bf16x4_t*)&hT[ch * HSTR + mt * 16 + lr * 4] = hv;
        }
    }
#pragma unroll
    for (int off = 1; off < 16; off <<= 1) {
#pragma unroll
        for (int mt = 0; mt < 5; ++mt)
#pragma unroll
            for (int j = 0; j < 4; ++j) {
                p0[mt][j] += __shfl_xor(p0[mt][j], off);
                p1[mt][j] += __shfl_xor(p1[mt][j], off);
            }
    }
    if (lc == 0) {
#pragma unroll
        for (int mt = 0; mt < 5; ++mt)
#pragma unroll
            for (int j = 0; j < 4; ++j) {
                attp0[w][mt * 16 + lr * 4 + j] = p0[mt][j];
                attp1[w][mt * 16 + lr * 4 + j] = p1[mt][j];
            }
    }
    __syncthreads();
    if (t < 80)       att0s[t]      = attp0[0][t] + attp0[1][t] + attp0[2][t] + attp0[3][t];
    else if (t < 160) att1s[t - 80] = attp1[0][t - 80] + attp1[1][t - 80] + attp1[2][t - 80] + attp1[3][t - 80];
    if (t < 250) ((unsigned*)(alp + 75 * HSTR))[t] = 0u;   // zero alp rows 75..79
    __syncthreads();

    // ---- phase S: masked softmax -> alp ----
    for (int i = w; i < NN; i += 4) {
        const float a0i = att0s[i];
        float e1;
        {
            float x = a0i + att1s[l];
            x = x > 0.f ? x : 0.2f * x;
            e1 = x - 1.0e9f * (1.f - (float)Adj[i * NN + l]);
        }
        float e2 = -INFINITY;
        if (l < NN - 64) {
            float x = a0i + att1s[l + 64];
            x = x > 0.f ? x : 0.2f * x;
            e2 = x - 1.0e9f * (1.f - (float)Adj[i * NN + l + 64]);
        }
        float mx = fmaxf(e1, e2);
#pragma unroll
        for (int off = 32; off; off >>= 1) mx = fmaxf(mx, __shfl_xor(mx, off));
        const float p1v = __expf(e1 - mx);
        const float p2v = (l < NN - 64) ? __expf(e2 - mx) : 0.f;
        float s = p1v + p2v;
#pragma unroll
        for (int off = 32; off; off >>= 1) s += __shfl_xor(s, off);
        const float rs = 1.f / s;

        alp[i * HSTR + l] = (bf16_t)(p1v * rs);
        if (l < 32)
            alp[i * HSTR + 64 + l] = (l < NN - 64) ? (bf16_t)(p2v * rs) : (bf16_t)0.f;
    }
    __syncthreads();

    // ---- phase P: out[i][ch] = sum_j alpha[i][j] hT[ch][j] via MFMA ----
    f32x4 acc2[5][4];
#pragma unroll
    for (int i = 0; i < 5; ++i)
#pragma unroll
        for (int j = 0; j < 4; ++j) acc2[i][j] = (f32x4){0.f, 0.f, 0.f, 0.f};

#pragma unroll
    for (int ks = 0; ks < 3; ++ks) {
        bf16x8 bv[4];
#pragma unroll
        for (int ntl = 0; ntl < 4; ++ntl) {
            const bf16_t* q = &hT[(w * 64 + ntl * 16 + lc) * HSTR + ks * 32 + lr * 8];
            ((uint2*)&bv[ntl])[0] = *(const uint2*)q;
            ((uint2*)&bv[ntl])[1] = *(const uint2*)(q + 4);
        }
#pragma unroll
        for (int mt = 0; mt < 5; ++mt) {
            const bf16_t* p = &alp[(mt * 16 + lc) * HSTR + ks * 32 + lr * 8];
            bf16x8 av;
            ((uint2*)&av)[0] = *(const uint2*)p;
            ((uint2*)&av)[1] = *(const uint2*)(p + 4);
#pragma unroll
            for (int ntl = 0; ntl < 4; ++ntl)
                acc2[mt][ntl] = __builtin_amdgcn_mfma_f32_16x16x32_bf16(av, bv[ntl], acc2[mt][ntl], 0, 0, 0);
        }
    }
#pragma unroll
    for (int mt = 0; mt < 5; ++mt)
#pragma unroll
        for (int ntl = 0; ntl < 4; ++ntl) {
            const int ch = w * 64 + ntl * 16 + lc;
#pragma unroll
            for (int j = 0; j < 4; ++j) {
                const int row = mt * 16 + lr * 4 + j;
                if (row < NN) outb[(size_t)row * 512 + ch] = acc2[mt][ntl][j];
            }
        }
}

// ---------------------------------------------------------------------------
extern "C" void kernel_launch(void* const* d_in, const int* in_sizes, int n_in,
                              void* d_out, int out_size, void* d_ws, size_t ws_size,
                              hipStream_t stream) {
    const float* X = (const float*)d_in[0];   // [1024,75,512] f32
    const int*   A = (const int*)d_in[1];     // [75,75] i32
    const float* W = (const float*)d_in[2];   // [512,256] f32
    const float* a = (const float*)d_in[3];   // [2,256,1] f32
    float* out = (float*)d_out;               // [1024,75,512] f32
    bf16_t* Wt = (bf16_t*)d_ws;               // 256 KB scratch

    wt_kernel<<<dim3(KF / 64, F1 / 64), 256, 0, stream>>>(W, Wt);
    fused_kernel<<<NB, 256, 0, stream>>>(X, Wt, A, a, out);
}